// Round 1
// baseline (828.639 us; speedup 1.0000x reference)
//
#include <hip/hip_runtime.h>
#include <hip/hip_bf16.h>
#include <math.h>

// RPMNet registration on MI355X.
// Shapes (from setup_inputs): B=16, J=K=1024, feat dim 6. num_reg_iter=3, num_sk_iter=5.
// Sinkhorn done in dual-potential form: u[j], v[k]; affinity recomputed on the fly
// (K=6 dot product) instead of materializing the 64MB matrix until the final write.

#define BATCH 16
#define NPTS  1024
#define REG_ITERS 3
#define SK_ITERS  5
#define EPS 1e-5f

// ---------- init: ref features (+sq norm) packed [B][N][8], transform = identity ----------
__global__ __launch_bounds__(256) void init_kernel(const float* __restrict__ pref,
                                                   float* __restrict__ fr,
                                                   float* __restrict__ T) {
    int idx = blockIdx.x * 256 + threadIdx.x;            // 0 .. B*N-1
    const float* p = pref + (size_t)idx * 6;
    float x0 = p[0], x1 = p[1], x2 = p[2], x3 = p[3], x4 = p[4], x5 = p[5];
    float sq = x0*x0 + x1*x1 + x2*x2 + x3*x3 + x4*x4 + x5*x5;
    float* o = fr + (size_t)idx * 8;
    o[0]=x0; o[1]=x1; o[2]=x2; o[3]=x3; o[4]=x4; o[5]=x5; o[6]=sq; o[7]=0.f;
    if (idx < BATCH * 12) {
        int i = idx % 12; int r = i >> 2; int c = i & 3;
        T[idx] = (r == c) ? 1.f : 0.f;
    }
}

// ---------- per reg-iter: src_t = R*xyz + t, pack feat [B][N][8], zero v ----------
__global__ __launch_bounds__(256) void precompute_src(const float* __restrict__ psrc,
                                                      const float* __restrict__ T,
                                                      float* __restrict__ fs,
                                                      float* __restrict__ v) {
    int idx = blockIdx.x * 256 + threadIdx.x;            // 0 .. B*N-1
    int b = idx >> 10;
    const float* p = psrc + (size_t)idx * 6;
    const float* t = T + b * 12;
    float x = p[0], y = p[1], z = p[2];
    float tx = t[0]*x + t[1]*y + t[2]*z  + t[3];
    float ty = t[4]*x + t[5]*y + t[6]*z  + t[7];
    float tz = t[8]*x + t[9]*y + t[10]*z + t[11];
    float f3 = p[3], f4 = p[4], f5 = p[5];
    float sq = tx*tx + ty*ty + tz*tz + f3*f3 + f4*f4 + f5*f5;
    float* o = fs + (size_t)idx * 8;
    o[0]=tx; o[1]=ty; o[2]=tz; o[3]=f3; o[4]=f4; o[5]=f5; o[6]=sq; o[7]=0.f;
    v[idx] = 0.f;
}

// ---------- dual potential update (used for both u and v by swapping operands) ----------
// pot_out[g] = log(1 + sum_k exp(-beta*(dist(fixed[g],other[k]) - alpha) - pot_other[k]))
__global__ __launch_bounds__(256) void pot_update(const float* __restrict__ fixed,
                                                  const float* __restrict__ other,
                                                  const float* __restrict__ pot_other,
                                                  float* __restrict__ pot_out,
                                                  const float* __restrict__ beta,
                                                  const float* __restrict__ alpha) {
    int gid  = blockIdx.x * 4 + (threadIdx.x >> 6);      // b*N + row
    int b    = gid >> 10;
    int lane = threadIdx.x & 63;
    const float4* fx = (const float4*)(fixed + (size_t)gid * 8);
    float4 f0 = fx[0], f1 = fx[1];
    float bet = beta[b], alp = alpha[b];
    const float* obase = other + ((size_t)b << 10) * 8;
    const float* pbase = pot_other + ((size_t)b << 10);
    float acc = 0.f;
    for (int k = lane; k < NPTS; k += 64) {
        float4 r0 = *(const float4*)(obase + (size_t)k * 8);
        float4 r1 = *(const float4*)(obase + (size_t)k * 8 + 4);
        float dot = f0.x*r0.x + f0.y*r0.y + f0.z*r0.z + f0.w*r0.w + f1.x*r1.x + f1.y*r1.y;
        float dist = f1.z + r1.z - 2.f * dot;
        float aff  = -bet * (dist - alp);
        acc += __expf(aff - pbase[k]);
    }
    for (int off = 32; off; off >>= 1) acc += __shfl_down(acc, off);
    if (lane == 0) pot_out[gid] = logf(1.f + acc);
}

// ---------- finalize: perm row sums + weighted-ref sums; optionally write perm ----------
template <bool WRITE_PERM>
__global__ __launch_bounds__(256) void finalize_kernel(const float* __restrict__ fs,
                                                       const float* __restrict__ fr,
                                                       const float* __restrict__ u,
                                                       const float* __restrict__ v,
                                                       const float* __restrict__ beta,
                                                       const float* __restrict__ alpha,
                                                       float* __restrict__ wsum,
                                                       float* __restrict__ wref,
                                                       float* __restrict__ perm_out) {
    int gid  = blockIdx.x * 4 + (threadIdx.x >> 6);      // b*N + j
    int b    = gid >> 10;
    int lane = threadIdx.x & 63;
    const float4* fx = (const float4*)(fs + (size_t)gid * 8);
    float4 f0 = fx[0], f1 = fx[1];
    float bet = beta[b], alp = alpha[b];
    float uj  = u[gid];
    const float* obase = fr + ((size_t)b << 10) * 8;
    const float* vbase = v + ((size_t)b << 10);
    float s = 0.f, sx = 0.f, sy = 0.f, sz = 0.f;
    for (int k = lane; k < NPTS; k += 64) {
        float4 r0 = *(const float4*)(obase + (size_t)k * 8);
        float4 r1 = *(const float4*)(obase + (size_t)k * 8 + 4);
        float dot = f0.x*r0.x + f0.y*r0.y + f0.z*r0.z + f0.w*r0.w + f1.x*r1.x + f1.y*r1.y;
        float dist = f1.z + r1.z - 2.f * dot;
        float p = __expf(-bet * (dist - alp) - uj - vbase[k]);
        s += p; sx += p * r0.x; sy += p * r0.y; sz += p * r0.z;
        if (WRITE_PERM) perm_out[(size_t)gid * NPTS + k] = p;
    }
    for (int off = 32; off; off >>= 1) {
        s  += __shfl_down(s, off);
        sx += __shfl_down(sx, off);
        sy += __shfl_down(sy, off);
        sz += __shfl_down(sz, off);
    }
    if (lane == 0) {
        wsum[gid] = s;
        wref[(size_t)gid * 4 + 0] = sx;
        wref[(size_t)gid * 4 + 1] = sy;
        wref[(size_t)gid * 4 + 2] = sz;
    }
}

// ---------- block reduction helper (256 threads) ----------
__device__ __forceinline__ float block_reduce_sum(float val, float* sbuf) {
    int lane = threadIdx.x & 63, wid = threadIdx.x >> 6;
    for (int off = 32; off; off >>= 1) val += __shfl_down(val, off);
    if (lane == 0) sbuf[wid] = val;
    __syncthreads();
    float r;
    if (threadIdx.x == 0) { r = sbuf[0] + sbuf[1] + sbuf[2] + sbuf[3]; sbuf[0] = r; }
    __syncthreads();
    r = sbuf[0];
    __syncthreads();
    return r;
}

// ---------- rigid transform (weighted Kabsch, SVD via Jacobi in double) ----------
__global__ __launch_bounds__(256) void rigid_kernel(const float* __restrict__ fs,
                                                    const float* __restrict__ wsum,
                                                    const float* __restrict__ wref,
                                                    float* __restrict__ T,
                                                    float* __restrict__ outT,
                                                    int write_out) {
    __shared__ float sbuf[4];
    int b = blockIdx.x, tid = threadIdx.x;

    float W = 0, A0 = 0, A1 = 0, A2 = 0, B0 = 0, B1 = 0, B2 = 0;
    for (int j = tid; j < NPTS; j += 256) {
        int g = (b << 10) + j;
        float w = wsum[g];
        const float* f = fs + (size_t)g * 8;
        float inv = 1.f / (w + EPS);
        float bx = wref[(size_t)g*4+0]*inv, by = wref[(size_t)g*4+1]*inv, bz = wref[(size_t)g*4+2]*inv;
        W += w;
        A0 += w*f[0]; A1 += w*f[1]; A2 += w*f[2];
        B0 += w*bx;   B1 += w*by;   B2 += w*bz;
    }
    W  = block_reduce_sum(W , sbuf);
    A0 = block_reduce_sum(A0, sbuf); A1 = block_reduce_sum(A1, sbuf); A2 = block_reduce_sum(A2, sbuf);
    B0 = block_reduce_sum(B0, sbuf); B1 = block_reduce_sum(B1, sbuf); B2 = block_reduce_sum(B2, sbuf);
    float D = W + EPS;
    float ca0 = A0/D, ca1 = A1/D, ca2 = A2/D;
    float cb0 = B0/D, cb1 = B1/D, cb2 = B2/D;

    float c00=0,c01=0,c02=0,c10=0,c11=0,c12=0,c20=0,c21=0,c22=0;
    for (int j = tid; j < NPTS; j += 256) {
        int g = (b << 10) + j;
        float w = wsum[g];
        const float* f = fs + (size_t)g * 8;
        float inv = 1.f / (w + EPS);
        float bx = wref[(size_t)g*4+0]*inv, by = wref[(size_t)g*4+1]*inv, bz = wref[(size_t)g*4+2]*inv;
        float wn = w / D;
        float a0 = f[0]-ca0, a1 = f[1]-ca1, a2 = f[2]-ca2;
        float bm0 = (bx-cb0)*wn, bm1 = (by-cb1)*wn, bm2 = (bz-cb2)*wn;
        c00 += a0*bm0; c01 += a0*bm1; c02 += a0*bm2;
        c10 += a1*bm0; c11 += a1*bm1; c12 += a1*bm2;
        c20 += a2*bm0; c21 += a2*bm1; c22 += a2*bm2;
    }
    c00 = block_reduce_sum(c00, sbuf); c01 = block_reduce_sum(c01, sbuf); c02 = block_reduce_sum(c02, sbuf);
    c10 = block_reduce_sum(c10, sbuf); c11 = block_reduce_sum(c11, sbuf); c12 = block_reduce_sum(c12, sbuf);
    c20 = block_reduce_sum(c20, sbuf); c21 = block_reduce_sum(c21, sbuf); c22 = block_reduce_sum(c22, sbuf);

    if (tid == 0) {
        double Am[3][3] = {{c00,c01,c02},{c10,c11,c12},{c20,c21,c22}};
        // S = Am^T Am
        double S[3][3];
        for (int i = 0; i < 3; ++i)
            for (int j2 = 0; j2 < 3; ++j2) {
                double acc = 0;
                for (int m = 0; m < 3; ++m) acc += Am[m][i] * Am[m][j2];
                S[i][j2] = acc;
            }
        double V[3][3] = {{1,0,0},{0,1,0},{0,0,1}};
        const int pr[3] = {0,0,1}, qr[3] = {1,2,2};
        for (int sweep = 0; sweep < 25; ++sweep) {
            double off = S[0][1]*S[0][1] + S[0][2]*S[0][2] + S[1][2]*S[1][2];
            if (off < 1e-28) break;
            for (int pi = 0; pi < 3; ++pi) {
                int p = pr[pi], q = qr[pi];
                double apq = S[p][q];
                if (fabs(apq) < 1e-300) continue;
                double theta = (S[q][q] - S[p][p]) / (2.0 * apq);
                double tt = ((theta >= 0) ? 1.0 : -1.0) / (fabs(theta) + sqrt(theta*theta + 1.0));
                double cth = 1.0 / sqrt(tt*tt + 1.0);
                double sth = tt * cth;
                for (int m = 0; m < 3; ++m) { double a1 = S[m][p], a2 = S[m][q]; S[m][p] = cth*a1 - sth*a2; S[m][q] = sth*a1 + cth*a2; }
                for (int m = 0; m < 3; ++m) { double a1 = S[p][m], a2 = S[q][m]; S[p][m] = cth*a1 - sth*a2; S[q][m] = sth*a1 + cth*a2; }
                for (int m = 0; m < 3; ++m) { double a1 = V[m][p], a2 = V[m][q]; V[m][p] = cth*a1 - sth*a2; V[m][q] = sth*a1 + cth*a2; }
            }
        }
        double lam[3] = {S[0][0], S[1][1], S[2][2]};
        int idx[3] = {0,1,2};
        if (lam[idx[0]] < lam[idx[1]]) { int t2 = idx[0]; idx[0] = idx[1]; idx[1] = t2; }
        if (lam[idx[0]] < lam[idx[2]]) { int t2 = idx[0]; idx[0] = idx[2]; idx[2] = t2; }
        if (lam[idx[1]] < lam[idx[2]]) { int t2 = idx[1]; idx[1] = idx[2]; idx[2] = t2; }
        double Vs[3][3], sv[3];
        for (int i = 0; i < 3; ++i) {
            int c = idx[i];
            for (int m = 0; m < 3; ++m) Vs[m][i] = V[m][c];
            double l = lam[c]; sv[i] = sqrt(l > 0 ? l : 0);
        }
        double Us[3][3];
        double smax = sv[0] > 1e-300 ? sv[0] : 1e-300;
        for (int i = 0; i < 3; ++i) {
            double ux = Am[0][0]*Vs[0][i] + Am[0][1]*Vs[1][i] + Am[0][2]*Vs[2][i];
            double uy = Am[1][0]*Vs[0][i] + Am[1][1]*Vs[1][i] + Am[1][2]*Vs[2][i];
            double uz = Am[2][0]*Vs[0][i] + Am[2][1]*Vs[1][i] + Am[2][2]*Vs[2][i];
            if (sv[i] > 1e-12 * smax) {
                Us[0][i] = ux/sv[i]; Us[1][i] = uy/sv[i]; Us[2][i] = uz/sv[i];
            } else {
                // degenerate smallest direction: complete with cross product
                double cx = Us[1][0]*Us[2][1] - Us[2][0]*Us[1][1];
                double cy = Us[2][0]*Us[0][1] - Us[0][0]*Us[2][1];
                double cz = Us[0][0]*Us[1][1] - Us[1][0]*Us[0][1];
                double n = sqrt(cx*cx + cy*cy + cz*cz); n = n > 1e-300 ? n : 1.0;
                Us[0][i] = cx/n; Us[1][i] = cy/n; Us[2][i] = cz/n;
            }
        }
        double M[3][3];
        for (int m = 0; m < 3; ++m)
            for (int n = 0; n < 3; ++n)
                M[m][n] = Vs[m][0]*Us[n][0] + Vs[m][1]*Us[n][1] + Vs[m][2]*Us[n][2];
        double det = M[0][0]*(M[1][1]*M[2][2]-M[1][2]*M[2][1])
                   - M[0][1]*(M[1][0]*M[2][2]-M[1][2]*M[2][0])
                   + M[0][2]*(M[1][0]*M[2][1]-M[1][1]*M[2][0]);
        double g3 = (det > 0.0) ? 1.0 : -1.0;
        double R[3][3];
        for (int m = 0; m < 3; ++m)
            for (int n = 0; n < 3; ++n)
                R[m][n] = Vs[m][0]*Us[n][0] + Vs[m][1]*Us[n][1] + g3*Vs[m][2]*Us[n][2];
        double ti[3];
        ti[0] = -(R[0][0]*ca0 + R[0][1]*ca1 + R[0][2]*ca2) + cb0;
        ti[1] = -(R[1][0]*ca0 + R[1][1]*ca1 + R[1][2]*ca2) + cb1;
        ti[2] = -(R[2][0]*ca0 + R[2][1]*ca1 + R[2][2]*ca2) + cb2;
        // compose with old transform: Rn = R*Ro; tn = R*to + ti
        float* Tb = T + b * 12;
        double Ro[3][3] = {{Tb[0],Tb[1],Tb[2]},{Tb[4],Tb[5],Tb[6]},{Tb[8],Tb[9],Tb[10]}};
        double to[3] = {Tb[3], Tb[7], Tb[11]};
        float Tn[12];
        for (int m = 0; m < 3; ++m) {
            for (int n = 0; n < 3; ++n)
                Tn[m*4+n] = (float)(R[m][0]*Ro[0][n] + R[m][1]*Ro[1][n] + R[m][2]*Ro[2][n]);
            Tn[m*4+3] = (float)(R[m][0]*to[0] + R[m][1]*to[1] + R[m][2]*to[2] + ti[m]);
        }
        for (int i = 0; i < 12; ++i) Tb[i] = Tn[i];
        if (write_out) for (int i = 0; i < 12; ++i) outT[b*12+i] = Tn[i];
    }
}

extern "C" void kernel_launch(void* const* d_in, const int* in_sizes, int n_in,
                              void* d_out, int out_size, void* d_ws, size_t ws_size,
                              hipStream_t stream) {
    const float* psrc  = (const float*)d_in[0];   // (16,1024,6)
    const float* pref  = (const float*)d_in[1];   // (16,1024,6)
    const float* beta  = (const float*)d_in[2];   // (16,)
    const float* alpha = (const float*)d_in[3];   // (16,)
    // d_in[4] = num_reg_iter = 3, d_in[5] = num_sk_iter = 5 (compile-time constants per setup_inputs)

    float* out     = (float*)d_out;
    float* outT    = out;                 // (16,3,4) = 192 floats
    float* outPerm = out + 192;           // (16,1024,1024)

    float* ws   = (float*)d_ws;           // ~1.5 MB used
    float* T    = ws;                     // 192 (padded to 256)
    float* fr   = ws + 256;               // 16*1024*8
    float* fs   = fr + BATCH*NPTS*8;      // 16*1024*8
    float* u    = fs + BATCH*NPTS*8;      // 16*1024
    float* v    = u  + BATCH*NPTS;        // 16*1024
    float* wsum = v  + BATCH*NPTS;        // 16*1024
    float* wref = wsum + BATCH*NPTS;      // 16*1024*4

    const int nBN = BATCH * NPTS;         // 16384
    init_kernel<<<nBN/256, 256, 0, stream>>>(pref, fr, T);
    for (int it = 0; it < REG_ITERS; ++it) {
        bool last = (it == REG_ITERS - 1);
        precompute_src<<<nBN/256, 256, 0, stream>>>(psrc, T, fs, v);
        for (int sk = 0; sk < SK_ITERS; ++sk) {
            pot_update<<<nBN/4, 256, 0, stream>>>(fs, fr, v, u, beta, alpha);  // row pass -> u
            pot_update<<<nBN/4, 256, 0, stream>>>(fr, fs, u, v, beta, alpha);  // col pass -> v
        }
        if (last)
            finalize_kernel<true ><<<nBN/4, 256, 0, stream>>>(fs, fr, u, v, beta, alpha, wsum, wref, outPerm);
        else
            finalize_kernel<false><<<nBN/4, 256, 0, stream>>>(fs, fr, u, v, beta, alpha, wsum, wref, outPerm);
        rigid_kernel<<<BATCH, 256, 0, stream>>>(fs, wsum, wref, T, outT, last ? 1 : 0);
    }
}

// Round 2
// 552.265 us; speedup vs baseline: 1.5004x; 1.5004x over previous
//
#include <hip/hip_runtime.h>
#include <hip/hip_bf16.h>
#include <math.h>

// RPMNet registration on MI355X. B=16, J=K=1024, feat 6. 3 reg iters x 5 sinkhorn iters.
// Sinkhorn in dual-potential form, base-2 log domain. Potentials stored in feature
// slot 7: u in fs[:,:,7], v in fr[:,:,7]. pot_update row-tiled 8 rows/wave so the
// k-stream (2 x float4 per k) is amortized across 8 rows.

#define BATCH 16
#define NPTS  1024
#define REG_ITERS 3
#define SK_ITERS  5
#define EPS 1e-5f
#define LOG2E 1.44269504088896f

// ---------- init: ref features (+sq norm) packed [B][N][8], slot7 = v = 0 ----------
__global__ __launch_bounds__(256) void init_kernel(const float* __restrict__ pref,
                                                   float* __restrict__ fr,
                                                   float* __restrict__ T) {
    int idx = blockIdx.x * 256 + threadIdx.x;            // 0 .. B*N-1
    const float* p = pref + (size_t)idx * 6;
    float x0 = p[0], x1 = p[1], x2 = p[2], x3 = p[3], x4 = p[4], x5 = p[5];
    float sq = x0*x0 + x1*x1 + x2*x2 + x3*x3 + x4*x4 + x5*x5;
    float* o = fr + (size_t)idx * 8;
    o[0]=x0; o[1]=x1; o[2]=x2; o[3]=x3; o[4]=x4; o[5]=x5; o[6]=sq; o[7]=0.f;
    if (idx < BATCH * 12) {
        int i = idx % 12; int r = i >> 2; int c = i & 3;
        T[idx] = (r == c) ? 1.f : 0.f;
    }
}

// ---------- per reg-iter: src_t = R*xyz + t, pack fs [B][N][8]; reset v (fr slot7) ----------
__global__ __launch_bounds__(256) void precompute_src(const float* __restrict__ psrc,
                                                      const float* __restrict__ T,
                                                      float* __restrict__ fs,
                                                      float* __restrict__ fr) {
    int idx = blockIdx.x * 256 + threadIdx.x;            // 0 .. B*N-1
    int b = idx >> 10;
    const float* p = psrc + (size_t)idx * 6;
    const float* t = T + b * 12;
    float x = p[0], y = p[1], z = p[2];
    float tx = t[0]*x + t[1]*y + t[2]*z  + t[3];
    float ty = t[4]*x + t[5]*y + t[6]*z  + t[7];
    float tz = t[8]*x + t[9]*y + t[10]*z + t[11];
    float f3 = p[3], f4 = p[4], f5 = p[5];
    float sq = tx*tx + ty*ty + tz*tz + f3*f3 + f4*f4 + f5*f5;
    float* o = fs + (size_t)idx * 8;
    o[0]=tx; o[1]=ty; o[2]=tz; o[3]=f3; o[4]=f4; o[5]=f5; o[6]=sq; o[7]=0.f;
    fr[(size_t)idx * 8 + 7] = 0.f;                       // v = 0 each reg iter
}

// ---------- dual potential update, row-tiled (8 rows per wave) ----------
// fixed[row][7] <- log2(1 + sum_k exp2(aff2(row,k) - other[k][7]))
// aff2 = bet2*(alpha - dist), bet2 = beta*log2(e)
__global__ __launch_bounds__(256) void pot_update(float* __restrict__ fixed,
                                                  const float* __restrict__ other,
                                                  const float* __restrict__ beta,
                                                  const float* __restrict__ alpha) {
    int wid = threadIdx.x >> 6, lane = threadIdx.x & 63;
    int row0 = blockIdx.x * 32 + wid * 8;                // global row base (b*N + j)
    int b = row0 >> 10;                                  // 32 | 1024 -> no batch straddle
    float bet2 = beta[b] * LOG2E;
    float alp  = alpha[b];
    float tb2  = 2.f * bet2;
    float fx[8], fy[8], fz[8], f3[8], f4[8], f5[8], c_row[8], acc[8];
    #pragma unroll
    for (int r = 0; r < 8; ++r) {
        const float* f = fixed + (size_t)(row0 + r) * 8;
        fx[r]=f[0]; fy[r]=f[1]; fz[r]=f[2]; f3[r]=f[3]; f4[r]=f[4]; f5[r]=f[5];
        c_row[r] = bet2 * (alp - f[6]);
        acc[r] = 0.f;
    }
    const float* obase = other + ((size_t)b << 10) * 8;
    for (int k = lane; k < NPTS; k += 64) {
        const float4* op = (const float4*)(obase + (size_t)k * 8);
        float4 r0 = op[0], r1 = op[1];
        float tk = fmaf(bet2, r1.z, r1.w);               // bet2*r_sq + pot_other[k]
        #pragma unroll
        for (int r = 0; r < 8; ++r) {
            float d = fx[r]*r0.x + fy[r]*r0.y + fz[r]*r0.z
                    + f3[r]*r0.w + f4[r]*r1.x + f5[r]*r1.y;
            acc[r] += __builtin_amdgcn_exp2f(fmaf(tb2, d, c_row[r] - tk));
        }
    }
    #pragma unroll
    for (int r = 0; r < 8; ++r) {
        float a = acc[r];
        for (int off = 32; off; off >>= 1) a += __shfl_down(a, off);
        if (lane == 0) fixed[(size_t)(row0 + r) * 8 + 7] = __builtin_amdgcn_logf(1.f + a);
    }
}

// ---------- finalize: perm row sums + weighted-ref sums; optionally write perm ----------
template <bool WRITE_PERM>
__global__ __launch_bounds__(256) void finalize_kernel(const float* __restrict__ fs,
                                                       const float* __restrict__ fr,
                                                       const float* __restrict__ beta,
                                                       const float* __restrict__ alpha,
                                                       float* __restrict__ wsum,
                                                       float* __restrict__ wref,
                                                       float* __restrict__ perm_out) {
    int wid = threadIdx.x >> 6, lane = threadIdx.x & 63;
    int row0 = blockIdx.x * 16 + wid * 4;                // 4 rows per wave
    int b = row0 >> 10;
    float bet2 = beta[b] * LOG2E;
    float alp  = alpha[b];
    float tb2  = 2.f * bet2;
    float fx[4], fy[4], fz[4], f3[4], f4[4], f5[4], c_row[4];
    float s[4], sx[4], sy[4], sz[4];
    #pragma unroll
    for (int r = 0; r < 4; ++r) {
        const float* f = fs + (size_t)(row0 + r) * 8;
        fx[r]=f[0]; fy[r]=f[1]; fz[r]=f[2]; f3[r]=f[3]; f4[r]=f[4]; f5[r]=f[5];
        c_row[r] = bet2 * (alp - f[6]) - f[7];           // includes -u2
        s[r]=0.f; sx[r]=0.f; sy[r]=0.f; sz[r]=0.f;
    }
    const float* obase = fr + ((size_t)b << 10) * 8;
    for (int k = lane; k < NPTS; k += 64) {
        const float4* op = (const float4*)(obase + (size_t)k * 8);
        float4 r0 = op[0], r1 = op[1];
        float tk = fmaf(bet2, r1.z, r1.w);               // bet2*r_sq + v2[k]
        #pragma unroll
        for (int r = 0; r < 4; ++r) {
            float d = fx[r]*r0.x + fy[r]*r0.y + fz[r]*r0.z
                    + f3[r]*r0.w + f4[r]*r1.x + f5[r]*r1.y;
            float p = __builtin_amdgcn_exp2f(fmaf(tb2, d, c_row[r] - tk));
            s[r] += p; sx[r] += p * r0.x; sy[r] += p * r0.y; sz[r] += p * r0.z;
            if (WRITE_PERM) perm_out[(size_t)(row0 + r) * NPTS + k] = p;
        }
    }
    #pragma unroll
    for (int r = 0; r < 4; ++r) {
        float a = s[r], b0 = sx[r], b1 = sy[r], b2 = sz[r];
        for (int off = 32; off; off >>= 1) {
            a  += __shfl_down(a,  off);
            b0 += __shfl_down(b0, off);
            b1 += __shfl_down(b1, off);
            b2 += __shfl_down(b2, off);
        }
        if (lane == 0) {
            int g = row0 + r;
            wsum[g] = a;
            wref[(size_t)g * 4 + 0] = b0;
            wref[(size_t)g * 4 + 1] = b1;
            wref[(size_t)g * 4 + 2] = b2;
        }
    }
}

// ---------- block reduction helper (256 threads) ----------
__device__ __forceinline__ float block_reduce_sum(float val, float* sbuf) {
    int lane = threadIdx.x & 63, wid = threadIdx.x >> 6;
    for (int off = 32; off; off >>= 1) val += __shfl_down(val, off);
    if (lane == 0) sbuf[wid] = val;
    __syncthreads();
    float r;
    if (threadIdx.x == 0) { r = sbuf[0] + sbuf[1] + sbuf[2] + sbuf[3]; sbuf[0] = r; }
    __syncthreads();
    r = sbuf[0];
    __syncthreads();
    return r;
}

// ---------- rigid transform (weighted Kabsch, SVD via Jacobi in double) ----------
__global__ __launch_bounds__(256) void rigid_kernel(const float* __restrict__ fs,
                                                    const float* __restrict__ wsum,
                                                    const float* __restrict__ wref,
                                                    float* __restrict__ T,
                                                    float* __restrict__ outT,
                                                    int write_out) {
    __shared__ float sbuf[4];
    int b = blockIdx.x, tid = threadIdx.x;

    float W = 0, A0 = 0, A1 = 0, A2 = 0, B0 = 0, B1 = 0, B2 = 0;
    for (int j = tid; j < NPTS; j += 256) {
        int g = (b << 10) + j;
        float w = wsum[g];
        const float* f = fs + (size_t)g * 8;
        float inv = 1.f / (w + EPS);
        float bx = wref[(size_t)g*4+0]*inv, by = wref[(size_t)g*4+1]*inv, bz = wref[(size_t)g*4+2]*inv;
        W += w;
        A0 += w*f[0]; A1 += w*f[1]; A2 += w*f[2];
        B0 += w*bx;   B1 += w*by;   B2 += w*bz;
    }
    W  = block_reduce_sum(W , sbuf);
    A0 = block_reduce_sum(A0, sbuf); A1 = block_reduce_sum(A1, sbuf); A2 = block_reduce_sum(A2, sbuf);
    B0 = block_reduce_sum(B0, sbuf); B1 = block_reduce_sum(B1, sbuf); B2 = block_reduce_sum(B2, sbuf);
    float D = W + EPS;
    float ca0 = A0/D, ca1 = A1/D, ca2 = A2/D;
    float cb0 = B0/D, cb1 = B1/D, cb2 = B2/D;

    float c00=0,c01=0,c02=0,c10=0,c11=0,c12=0,c20=0,c21=0,c22=0;
    for (int j = tid; j < NPTS; j += 256) {
        int g = (b << 10) + j;
        float w = wsum[g];
        const float* f = fs + (size_t)g * 8;
        float inv = 1.f / (w + EPS);
        float bx = wref[(size_t)g*4+0]*inv, by = wref[(size_t)g*4+1]*inv, bz = wref[(size_t)g*4+2]*inv;
        float wn = w / D;
        float a0 = f[0]-ca0, a1 = f[1]-ca1, a2 = f[2]-ca2;
        float bm0 = (bx-cb0)*wn, bm1 = (by-cb1)*wn, bm2 = (bz-cb2)*wn;
        c00 += a0*bm0; c01 += a0*bm1; c02 += a0*bm2;
        c10 += a1*bm0; c11 += a1*bm1; c12 += a1*bm2;
        c20 += a2*bm0; c21 += a2*bm1; c22 += a2*bm2;
    }
    c00 = block_reduce_sum(c00, sbuf); c01 = block_reduce_sum(c01, sbuf); c02 = block_reduce_sum(c02, sbuf);
    c10 = block_reduce_sum(c10, sbuf); c11 = block_reduce_sum(c11, sbuf); c12 = block_reduce_sum(c12, sbuf);
    c20 = block_reduce_sum(c20, sbuf); c21 = block_reduce_sum(c21, sbuf); c22 = block_reduce_sum(c22, sbuf);

    if (tid == 0) {
        double Am[3][3] = {{c00,c01,c02},{c10,c11,c12},{c20,c21,c22}};
        double S[3][3];
        for (int i = 0; i < 3; ++i)
            for (int j2 = 0; j2 < 3; ++j2) {
                double acc = 0;
                for (int m = 0; m < 3; ++m) acc += Am[m][i] * Am[m][j2];
                S[i][j2] = acc;
            }
        double V[3][3] = {{1,0,0},{0,1,0},{0,0,1}};
        const int pr[3] = {0,0,1}, qr[3] = {1,2,2};
        for (int sweep = 0; sweep < 25; ++sweep) {
            double off = S[0][1]*S[0][1] + S[0][2]*S[0][2] + S[1][2]*S[1][2];
            if (off < 1e-28) break;
            for (int pi = 0; pi < 3; ++pi) {
                int p = pr[pi], q = qr[pi];
                double apq = S[p][q];
                if (fabs(apq) < 1e-300) continue;
                double theta = (S[q][q] - S[p][p]) / (2.0 * apq);
                double tt = ((theta >= 0) ? 1.0 : -1.0) / (fabs(theta) + sqrt(theta*theta + 1.0));
                double cth = 1.0 / sqrt(tt*tt + 1.0);
                double sth = tt * cth;
                for (int m = 0; m < 3; ++m) { double a1 = S[m][p], a2 = S[m][q]; S[m][p] = cth*a1 - sth*a2; S[m][q] = sth*a1 + cth*a2; }
                for (int m = 0; m < 3; ++m) { double a1 = S[p][m], a2 = S[q][m]; S[p][m] = cth*a1 - sth*a2; S[q][m] = sth*a1 + cth*a2; }
                for (int m = 0; m < 3; ++m) { double a1 = V[m][p], a2 = V[m][q]; V[m][p] = cth*a1 - sth*a2; V[m][q] = sth*a1 + cth*a2; }
            }
        }
        double lam[3] = {S[0][0], S[1][1], S[2][2]};
        int idx[3] = {0,1,2};
        if (lam[idx[0]] < lam[idx[1]]) { int t2 = idx[0]; idx[0] = idx[1]; idx[1] = t2; }
        if (lam[idx[0]] < lam[idx[2]]) { int t2 = idx[0]; idx[0] = idx[2]; idx[2] = t2; }
        if (lam[idx[1]] < lam[idx[2]]) { int t2 = idx[1]; idx[1] = idx[2]; idx[2] = t2; }
        double Vs[3][3], sv[3];
        for (int i = 0; i < 3; ++i) {
            int c = idx[i];
            for (int m = 0; m < 3; ++m) Vs[m][i] = V[m][c];
            double l = lam[c]; sv[i] = sqrt(l > 0 ? l : 0);
        }
        double Us[3][3];
        double smax = sv[0] > 1e-300 ? sv[0] : 1e-300;
        for (int i = 0; i < 3; ++i) {
            double ux = Am[0][0]*Vs[0][i] + Am[0][1]*Vs[1][i] + Am[0][2]*Vs[2][i];
            double uy = Am[1][0]*Vs[0][i] + Am[1][1]*Vs[1][i] + Am[1][2]*Vs[2][i];
            double uz = Am[2][0]*Vs[0][i] + Am[2][1]*Vs[1][i] + Am[2][2]*Vs[2][i];
            if (sv[i] > 1e-12 * smax) {
                Us[0][i] = ux/sv[i]; Us[1][i] = uy/sv[i]; Us[2][i] = uz/sv[i];
            } else {
                double cx = Us[1][0]*Us[2][1] - Us[2][0]*Us[1][1];
                double cy = Us[2][0]*Us[0][1] - Us[0][0]*Us[2][1];
                double cz = Us[0][0]*Us[1][1] - Us[1][0]*Us[0][1];
                double n = sqrt(cx*cx + cy*cy + cz*cz); n = n > 1e-300 ? n : 1.0;
                Us[0][i] = cx/n; Us[1][i] = cy/n; Us[2][i] = cz/n;
            }
        }
        double M[3][3];
        for (int m = 0; m < 3; ++m)
            for (int n = 0; n < 3; ++n)
                M[m][n] = Vs[m][0]*Us[n][0] + Vs[m][1]*Us[n][1] + Vs[m][2]*Us[n][2];
        double det = M[0][0]*(M[1][1]*M[2][2]-M[1][2]*M[2][1])
                   - M[0][1]*(M[1][0]*M[2][2]-M[1][2]*M[2][0])
                   + M[0][2]*(M[1][0]*M[2][1]-M[1][1]*M[2][0]);
        double g3 = (det > 0.0) ? 1.0 : -1.0;
        double R[3][3];
        for (int m = 0; m < 3; ++m)
            for (int n = 0; n < 3; ++n)
                R[m][n] = Vs[m][0]*Us[n][0] + Vs[m][1]*Us[n][1] + g3*Vs[m][2]*Us[n][2];
        double ti[3];
        ti[0] = -(R[0][0]*ca0 + R[0][1]*ca1 + R[0][2]*ca2) + cb0;
        ti[1] = -(R[1][0]*ca0 + R[1][1]*ca1 + R[1][2]*ca2) + cb1;
        ti[2] = -(R[2][0]*ca0 + R[2][1]*ca1 + R[2][2]*ca2) + cb2;
        float* Tb = T + b * 12;
        double Ro[3][3] = {{Tb[0],Tb[1],Tb[2]},{Tb[4],Tb[5],Tb[6]},{Tb[8],Tb[9],Tb[10]}};
        double to[3] = {Tb[3], Tb[7], Tb[11]};
        float Tn[12];
        for (int m = 0; m < 3; ++m) {
            for (int n = 0; n < 3; ++n)
                Tn[m*4+n] = (float)(R[m][0]*Ro[0][n] + R[m][1]*Ro[1][n] + R[m][2]*Ro[2][n]);
            Tn[m*4+3] = (float)(R[m][0]*to[0] + R[m][1]*to[1] + R[m][2]*to[2] + ti[m]);
        }
        for (int i = 0; i < 12; ++i) Tb[i] = Tn[i];
        if (write_out) for (int i = 0; i < 12; ++i) outT[b*12+i] = Tn[i];
    }
}

extern "C" void kernel_launch(void* const* d_in, const int* in_sizes, int n_in,
                              void* d_out, int out_size, void* d_ws, size_t ws_size,
                              hipStream_t stream) {
    const float* psrc  = (const float*)d_in[0];   // (16,1024,6)
    const float* pref  = (const float*)d_in[1];   // (16,1024,6)
    const float* beta  = (const float*)d_in[2];   // (16,)
    const float* alpha = (const float*)d_in[3];   // (16,)

    float* out     = (float*)d_out;
    float* outT    = out;                 // (16,3,4) = 192 floats
    float* outPerm = out + 192;           // (16,1024,1024)

    float* ws   = (float*)d_ws;
    float* T    = ws;                     // 192 (padded to 256)
    float* fr   = ws + 256;               // 16*1024*8
    float* fs   = fr + BATCH*NPTS*8;      // 16*1024*8
    float* wsum = fs + BATCH*NPTS*8;      // 16*1024
    float* wref = wsum + BATCH*NPTS;      // 16*1024*4

    const int nBN = BATCH * NPTS;         // 16384
    init_kernel<<<nBN/256, 256, 0, stream>>>(pref, fr, T);
    for (int it = 0; it < REG_ITERS; ++it) {
        bool last = (it == REG_ITERS - 1);
        precompute_src<<<nBN/256, 256, 0, stream>>>(psrc, T, fs, fr);
        for (int sk = 0; sk < SK_ITERS; ++sk) {
            pot_update<<<nBN/32, 256, 0, stream>>>(fs, fr, beta, alpha);  // row pass -> u (fs slot7)
            pot_update<<<nBN/32, 256, 0, stream>>>(fr, fs, beta, alpha);  // col pass -> v (fr slot7)
        }
        if (last)
            finalize_kernel<true ><<<nBN/16, 256, 0, stream>>>(fs, fr, beta, alpha, wsum, wref, outPerm);
        else
            finalize_kernel<false><<<nBN/16, 256, 0, stream>>>(fs, fr, beta, alpha, wsum, wref, outPerm);
        rigid_kernel<<<BATCH, 256, 0, stream>>>(fs, wsum, wref, T, outT, last ? 1 : 0);
    }
}